// Round 5
// baseline (169.746 us; speedup 1.0000x reference)
//
#include <hip/hip_runtime.h>
#include <math.h>

#define N_SAMPLES 8192
#define DIM 128
#define NCLS 1024
#define MARGIN_V 0.3f
#define DIST_GX (N_SAMPLES / 128)   // 64 j-tiles of 128
#define DIST_GY (NCLS / 64)         // 16 class-tiles of 64
#define NPART DIST_GX               // 64 partials per class
#define NBLK (DIST_GX * DIST_GY)    // 1024 dist blocks
#define MAXMEM 64                   // LDS member-list capacity per class
#define PIPE 16                     // pipelined gather depth (covers P(cnt<=16)~0.997)

using bf16x8 = __attribute__((ext_vector_type(8))) short;
using f32x16 = __attribute__((ext_vector_type(16))) float;
using short8 = __attribute__((ext_vector_type(8))) short;

__device__ __forceinline__ short bf16_rne(float x) {
  unsigned u = __float_as_uint(x);
  unsigned r = u + 0x7FFFu + ((u >> 16) & 1u);
  return (short)(r >> 16);
}

// Packed fragment layout, single bf16 plane (row-major source [row][k]):
//   tile = row>>5, kstep = oct>>1 (oct = k/8), lane = ((oct&1)<<5)|(row&31)
//   short8 index = (tile*8 + kstep)*64 + lane
// Matches mfma_32x32x16 A/B operand layout operand[row=lane&31][k=(lane>>5)*8+j]
// (harness-verified; bf16-only passes with absmax ~0).
__device__ __forceinline__ size_t frag_idx(int row, int oct) {
  int tile = row >> 5, ks = oct >> 1, lane = ((oct & 1) << 5) | (row & 31);
  return (size_t)(tile * 8 + ks) * 64 + lane;
}

// K1: fused pack (R4-verified body + int4 target scan + ctr zeroing).
// Blocks [0,512): B-side — x2 + bf16 pack of 16 input rows.
// Blocks [512,1024): A-side — 2 classes/block. Block 0 zeroes the K2
// done-counter (stream order makes it visible to K2; R3-verified pattern).
__global__ __launch_bounds__(256) void pack_kernel(
    const float* __restrict__ inputs, const int* __restrict__ targets,
    float* __restrict__ x2, float* __restrict__ c2, int* __restrict__ counts,
    short8* __restrict__ Apk, short8* __restrict__ Bpk, int* __restrict__ ctr) {
  int b = blockIdx.x;
  int tid = threadIdx.x;
  if (b == 0 && tid == 0) ctr[0] = 0;
  if (b < N_SAMPLES / 16) {
    int row = b * 16 + (tid >> 4);
    int oct = tid & 15;
    const float4* p = (const float4*)(inputs + (size_t)row * DIM + oct * 8);
    float4 v0 = p[0], v1 = p[1];
    float v[8] = {v0.x, v0.y, v0.z, v0.w, v1.x, v1.y, v1.z, v1.w};
    float s = 0.f;
    #pragma unroll
    for (int i = 0; i < 8; i++) s += v[i] * v[i];
    #pragma unroll
    for (int m = 1; m < 16; m <<= 1) s += __shfl_xor(s, m);
    if (oct == 0) x2[row] = s;
    short8 hi;
    #pragma unroll
    for (int i = 0; i < 8; i++) hi[i] = bf16_rne(v[i]);
    Bpk[frag_idx(row, oct)] = hi;
  } else {
    __shared__ int mem[2][MAXMEM];
    __shared__ int mcnt[2];
    __shared__ float sctr[2][128];
    __shared__ float wsum[4];
    int c0 = (b - N_SAMPLES / 16) * 2;
    if (tid < 2) { mcnt[tid] = 0; mem[tid][0] = 0; }  // mem[.][0] valid even if cnt==0
    __syncthreads();
    // Vectorized batch scan: 8 x dwordx4 per thread (G13), all in flight
    // before the LDS-atomic compare loop. Element j = 4*(tid+256*q)+e.
    const int4* tv = (const int4*)targets;
    int4 tg[8];
    #pragma unroll
    for (int q = 0; q < 8; q++) tg[q] = tv[tid + 256 * q];
    #pragma unroll
    for (int q = 0; q < 8; q++) {
      int base = 4 * (tid + 256 * q);
      int te[4] = {tg[q].x, tg[q].y, tg[q].z, tg[q].w};
      #pragma unroll
      for (int e = 0; e < 4; e++) {
        if (te[e] == c0) {
          int p = atomicAdd(&mcnt[0], 1);
          if (p < MAXMEM) mem[0][p] = base + e;
        } else if (te[e] == c0 + 1) {
          int p = atomicAdd(&mcnt[1], 1);
          if (p < MAXMEM) mem[1][p] = base + e;
        }
      }
    }
    __syncthreads();
    int half = tid >> 7;
    int c = c0 + half;
    int d = tid & 127;
    int cnt = mcnt[half];
    int cl = (cnt < MAXMEM) ? cnt : MAXMEM;
    int n1 = (cl < PIPE) ? cl : PIPE;
    int idxs[PIPE];
    #pragma unroll
    for (int i = 0; i < PIPE; i++) idxs[i] = mem[half][(i < n1) ? i : 0];
    float vbuf[PIPE];
    #pragma unroll
    for (int i = 0; i < PIPE; i++) vbuf[i] = inputs[(size_t)idxs[i] * DIM + d];
    float acc = 0.f;
    #pragma unroll
    for (int i = 0; i < PIPE; i++) if (i < n1) acc += vbuf[i];
    for (int m = PIPE; m < cl; m++) acc += inputs[(size_t)mem[half][m] * DIM + d];
    float ctrv = (cnt > 0) ? acc / (float)cnt : 0.f;
    sctr[half][d] = ctrv;
    float vv = ctrv * ctrv;
    #pragma unroll
    for (int sh = 32; sh > 0; sh >>= 1) vv += __shfl_down(vv, sh);
    if ((tid & 63) == 0) wsum[tid >> 6] = vv;
    __syncthreads();
    if (d == 0) {
      c2[c] = wsum[half * 2] + wsum[half * 2 + 1];
      counts[c] = cnt;
    }
    if (d < 16) {
      int oct = d;
      short8 hi;
      #pragma unroll
      for (int i = 0; i < 8; i++) hi[i] = bf16_rne(sctr[half][oct * 8 + i]);
      Apk[frag_idx(c, oct)] = hi;
    }
  }
}

// K2: MFMA dist (R4-verified prefetch-all + operand-swap body) + fused
// finalize via the NON-BLOCKING last-block pattern. Partials are PLAIN
// coalesced stores (R3's regression was the 64-way-contended far atomicMax,
// not the fence/counter — which R3 proved correct). Per block: stores ->
// __syncthreads (vmcnt drain) -> tid0 __threadfence (agent release, L2
// writeback) -> done-counter add. The block seeing prev==NBLK-1 does an
// acquire fence and runs the R4-verified finalize over all 16 class-groups,
// writing out[] directly. No thread ever waits on another block.
__global__ __launch_bounds__(256, 3) void dist_kernel(
    const short8* __restrict__ Apk, const short8* __restrict__ Bpk,
    const float* __restrict__ x2, const float* __restrict__ c2,
    const int* __restrict__ targets, const int* __restrict__ counts,
    float* __restrict__ dp_part, float* __restrict__ dn_part,
    int* __restrict__ ctr, float* __restrict__ out) {
  __shared__ float sc2[64];
  __shared__ float sx2[128];
  __shared__ int stgt[128];
  __shared__ float redp[2][2][32];  // [wn][wm][class-in-tile]
  __shared__ float redn[2][2][32];
  __shared__ float sdp[4][64];      // finalize staging (last block only)
  __shared__ float sdn[4][64];
  __shared__ int s_last;

  int tid = threadIdx.x;
  int jbase = blockIdx.x * 128;
  int cbase = blockIdx.y * 64;
  int wave = tid >> 6, lane = tid & 63;
  int wm = wave >> 1, wn = wave & 1;

  if (tid < 128) {
    sx2[tid] = x2[jbase + tid];
    stgt[tid] = targets[jbase + tid];
  }
  if (tid < 64) sc2[tid] = c2[cbase + tid];

  int mtg = (cbase >> 5) + wm;       // this wave's m-tile in Apk
  int ntg0 = (jbase >> 5) + wn * 2;  // first of 2 n-tiles in Bpk

  // ---- prefetch-all: 24 loads in flight (3 bases + immediate offsets) ----
  const short8* abase  = &Apk[(size_t)(mtg * 8) * 64 + lane];
  const short8* b0base = &Bpk[(size_t)((ntg0 + 0) * 8) * 64 + lane];
  const short8* b1base = &Bpk[(size_t)((ntg0 + 1) * 8) * 64 + lane];
  bf16x8 av[8], b0[8], b1[8];
  #pragma unroll
  for (int ks = 0; ks < 8; ks++) {
    av[ks] = abase[(size_t)ks * 64];    // offset ks*1024 B (13-bit imm fits)
    b0[ks] = b0base[(size_t)ks * 64];
    b1[ks] = b1base[(size_t)ks * 64];
  }

  f32x16 acc[2];
  acc[0] = (f32x16)(0.f);
  acc[1] = (f32x16)(0.f);

  // Swapped operands: D[row=j][col=class].
  #pragma unroll
  for (int ks = 0; ks < 8; ks++) {
    acc[0] = __builtin_amdgcn_mfma_f32_32x32x16_bf16(b0[ks], av[ks], acc[0], 0, 0, 0);
    acc[1] = __builtin_amdgcn_mfma_f32_32x32x16_bf16(b1[ks], av[ks], acc[1], 0, 0, 0);
  }

  __syncthreads();  // staging visible

  // ---- lane-local epilogue: lane owns class col=lane&31; regs span j ----
  int col = lane & 31;
  int hf = lane >> 5;
  int c_loc = wm * 32 + col;
  int cg = cbase + c_loc;
  float c2v = sc2[c_loc];
  float pmax = -INFINITY, nmin = INFINITY;
  #pragma unroll
  for (int nt = 0; nt < 2; nt++) {
    #pragma unroll
    for (int r = 0; r < 16; r++) {
      int j_loc = wn * 64 + nt * 32 + (r & 3) + 8 * (r >> 2) + 4 * hf;
      float d2 = c2v + sx2[j_loc] - 2.f * acc[nt][r];
      if (stgt[j_loc] == cg) pmax = fmaxf(pmax, d2);
      else                   nmin = fminf(nmin, d2);
    }
  }
  // fold the two hf halves (same class, disjoint j sets)
  pmax = fmaxf(pmax, __shfl_xor(pmax, 32));
  nmin = fminf(nmin, __shfl_xor(nmin, 32));
  if (lane < 32) {
    redp[wn][wm][col] = pmax;
    redn[wn][wm][col] = nmin;
  }
  __syncthreads();
  if (tid < 64) {  // one thread per class in this block's 64-class tile
    int wmx = tid >> 5, idx = tid & 31;
    float dp = fmaxf(redp[0][wmx][idx], redp[1][wmx][idx]);
    float dn = fminf(redn[0][wmx][idx], redn[1][wmx][idx]);
    size_t slot = (size_t)blockIdx.x * NCLS + cbase + tid;
    dp_part[slot] = dp;
    dn_part[slot] = dn;
  }

  // ---- non-blocking done-counter; last-finishing block finalizes ----
  __syncthreads();  // drains this block's partial stores (vmcnt(0))
  if (tid == 0) {
    __threadfence();  // agent release: partials visible device-wide
    int prev = __hip_atomic_fetch_add(ctr, 1, __ATOMIC_ACQ_REL,
                                      __HIP_MEMORY_SCOPE_AGENT);
    s_last = (prev == NBLK - 1) ? 1 : 0;
  }
  __syncthreads();
  if (!s_last) return;
  __threadfence();  // acquire: all blocks' partials now readable

  // Finalize (R4-verified logic, looped over the 16 class-groups).
  float ls_acc = 0.f, ps_acc = 0.f;
  for (int g = 0; g < 16; g++) {
    int cl = tid & 63;
    int pg = tid >> 6;
    int c = g * 64 + cl;
    float dp = -INFINITY, dn = INFINITY;
    #pragma unroll
    for (int p = pg * 16; p < pg * 16 + 16; p++) {
      dp = fmaxf(dp, dp_part[(size_t)p * NCLS + c]);
      dn = fminf(dn, dn_part[(size_t)p * NCLS + c]);
    }
    sdp[pg][cl] = dp;
    sdn[pg][cl] = dn;
    __syncthreads();
    if (tid < 64) {
      float dpf = fmaxf(fmaxf(sdp[0][tid], sdp[1][tid]), fmaxf(sdp[2][tid], sdp[3][tid]));
      float dnf = fminf(fminf(sdn[0][tid], sdn[1][tid]), fminf(sdn[2][tid], sdn[3][tid]));
      int cnt = counts[g * 64 + tid];
      if (cnt > 0) {
        ls_acc += (float)cnt * fmaxf(dpf - dnf + MARGIN_V, 0.f);
        ps_acc += (float)cnt * ((dnf > dpf) ? 1.f : 0.f);
      }
    }
    __syncthreads();
  }
  if (tid < 64) {
    #pragma unroll
    for (int sh = 32; sh > 0; sh >>= 1) {
      ls_acc += __shfl_down(ls_acc, sh);
      ps_acc += __shfl_down(ps_acc, sh);
    }
    if (tid == 0) {
      out[0] = ls_acc / (float)N_SAMPLES;
      out[1] = ps_acc / (float)N_SAMPLES;
    }
  }
}

extern "C" void kernel_launch(void* const* d_in, const int* in_sizes, int n_in,
                              void* d_out, int out_size, void* d_ws, size_t ws_size,
                              hipStream_t stream) {
  const float* inputs = (const float*)d_in[0];
  const int* targets = (const int*)d_in[1];
  float* out = (float*)d_out;

  char* w = (char*)d_ws;
  int* ctr = (int*)w;               w += 16;                          // done counter
  float* x2 = (float*)w;            w += (size_t)N_SAMPLES * 4;
  float* c2 = (float*)w;            w += (size_t)NCLS * 4;
  int* counts = (int*)w;            w += (size_t)NCLS * 4;
  float* dp_part = (float*)w;       w += (size_t)NPART * NCLS * 4;    // 256 KB
  float* dn_part = (float*)w;       w += (size_t)NPART * NCLS * 4;    // 256 KB
  short8* Apk = (short8*)w;         w += (size_t)NCLS * DIM * 2;      // 256 KB
  short8* Bpk = (short8*)w;         w += (size_t)N_SAMPLES * DIM * 2; // 2 MB

  pack_kernel<<<N_SAMPLES / 16 + NCLS / 2, 256, 0, stream>>>(
      inputs, targets, x2, c2, counts, Apk, Bpk, ctr);
  dist_kernel<<<dim3(DIST_GX, DIST_GY), 256, 0, stream>>>(
      Apk, Bpk, x2, c2, targets, counts, dp_part, dn_part, ctr, out);
}

// Round 6
// 70.230 us; speedup vs baseline: 2.4170x; 2.4170x over previous
//
#include <hip/hip_runtime.h>
#include <math.h>

#define N_SAMPLES 8192
#define DIM 128
#define NCLS 1024
#define MARGIN_V 0.3f
#define DIST_GX (N_SAMPLES / 128)   // 64 j-tiles of 128
#define DIST_GY (NCLS / 64)         // 16 class-tiles of 64
#define NPART DIST_GX               // 64 partials per class
#define MAXMEM 64                   // LDS member-list capacity per class
#define PIPE 16                     // pipelined gather depth (covers P(cnt<=16)~0.997)

using bf16x8 = __attribute__((ext_vector_type(8))) short;
using f32x16 = __attribute__((ext_vector_type(16))) float;
using short8 = __attribute__((ext_vector_type(8))) short;

// LESSON (R1/R2/R3/R5): in-kernel cross-block sync (spin barrier, cooperative
// launch, last-block + __threadfence) costs 40-100+ us on MI355X (agent-scope
// release = L2 writeback on non-coherent XCDs; fused tails also wreck the
// register allocation of the hot loop). Kernel boundaries cost ~2 us. Three
// plain kernels IS the optimal sync structure here. Do not re-fuse.

__device__ __forceinline__ short bf16_rne(float x) {
  unsigned u = __float_as_uint(x);
  unsigned r = u + 0x7FFFu + ((u >> 16) & 1u);
  return (short)(r >> 16);
}

// Packed fragment layout, single bf16 plane (row-major source [row][k]):
//   tile = row>>5, kstep = oct>>1 (oct = k/8), lane = ((oct&1)<<5)|(row&31)
//   short8 index = (tile*8 + kstep)*64 + lane
// Matches mfma_32x32x16 A/B operand layout operand[row=lane&31][k=(lane>>5)*8+j]
// (harness-verified; bf16-only passes with absmax ~0).
__device__ __forceinline__ size_t frag_idx(int row, int oct) {
  int tile = row >> 5, ks = oct >> 1, lane = ((oct & 1) << 5) | (row & 31);
  return (size_t)(tile * 8 + ks) * 64 + lane;
}

// K1: fused pack (R4-verified body; R5's int4 scan kept — strictly fewer
// load instructions, same coalescing). Blocks [0,512): B-side — x2 + bf16
// pack of 16 input rows. Blocks [512,1024): A-side — 2 classes/block.
// Block 0 zeroes out.
__global__ __launch_bounds__(256) void pack_kernel(
    const float* __restrict__ inputs, const int* __restrict__ targets,
    float* __restrict__ x2, float* __restrict__ c2, int* __restrict__ counts,
    short8* __restrict__ Apk, short8* __restrict__ Bpk, float* __restrict__ out) {
  int b = blockIdx.x;
  int tid = threadIdx.x;
  if (b == 0 && tid < 2) out[tid] = 0.f;
  if (b < N_SAMPLES / 16) {
    int row = b * 16 + (tid >> 4);
    int oct = tid & 15;
    const float4* p = (const float4*)(inputs + (size_t)row * DIM + oct * 8);
    float4 v0 = p[0], v1 = p[1];
    float v[8] = {v0.x, v0.y, v0.z, v0.w, v1.x, v1.y, v1.z, v1.w};
    float s = 0.f;
    #pragma unroll
    for (int i = 0; i < 8; i++) s += v[i] * v[i];
    #pragma unroll
    for (int m = 1; m < 16; m <<= 1) s += __shfl_xor(s, m);
    if (oct == 0) x2[row] = s;
    short8 hi;
    #pragma unroll
    for (int i = 0; i < 8; i++) hi[i] = bf16_rne(v[i]);
    Bpk[frag_idx(row, oct)] = hi;
  } else {
    __shared__ int mem[2][MAXMEM];
    __shared__ int mcnt[2];
    __shared__ float sctr[2][128];
    __shared__ float wsum[4];
    int c0 = (b - N_SAMPLES / 16) * 2;
    if (tid < 2) { mcnt[tid] = 0; mem[tid][0] = 0; }  // mem[.][0] valid even if cnt==0
    __syncthreads();
    // Vectorized batch scan: 8 x dwordx4 per thread, all in flight before
    // the LDS-atomic compare loop. Element j = 4*(tid+256*q)+e.
    const int4* tv = (const int4*)targets;
    int4 tg[8];
    #pragma unroll
    for (int q = 0; q < 8; q++) tg[q] = tv[tid + 256 * q];
    #pragma unroll
    for (int q = 0; q < 8; q++) {
      int base = 4 * (tid + 256 * q);
      int te[4] = {tg[q].x, tg[q].y, tg[q].z, tg[q].w};
      #pragma unroll
      for (int e = 0; e < 4; e++) {
        if (te[e] == c0) {
          int p = atomicAdd(&mcnt[0], 1);
          if (p < MAXMEM) mem[0][p] = base + e;
        } else if (te[e] == c0 + 1) {
          int p = atomicAdd(&mcnt[1], 1);
          if (p < MAXMEM) mem[1][p] = base + e;
        }
      }
    }
    __syncthreads();
    int half = tid >> 7;
    int c = c0 + half;
    int d = tid & 127;
    int cnt = mcnt[half];
    int cl = (cnt < MAXMEM) ? cnt : MAXMEM;
    int n1 = (cl < PIPE) ? cl : PIPE;
    int idxs[PIPE];
    #pragma unroll
    for (int i = 0; i < PIPE; i++) idxs[i] = mem[half][(i < n1) ? i : 0];
    float vbuf[PIPE];
    #pragma unroll
    for (int i = 0; i < PIPE; i++) vbuf[i] = inputs[(size_t)idxs[i] * DIM + d];
    float acc = 0.f;
    #pragma unroll
    for (int i = 0; i < PIPE; i++) if (i < n1) acc += vbuf[i];
    for (int m = PIPE; m < cl; m++) acc += inputs[(size_t)mem[half][m] * DIM + d];
    float ctrv = (cnt > 0) ? acc / (float)cnt : 0.f;
    sctr[half][d] = ctrv;
    float vv = ctrv * ctrv;
    #pragma unroll
    for (int sh = 32; sh > 0; sh >>= 1) vv += __shfl_down(vv, sh);
    if ((tid & 63) == 0) wsum[tid >> 6] = vv;
    __syncthreads();
    if (d == 0) {
      c2[c] = wsum[half * 2] + wsum[half * 2 + 1];
      counts[c] = cnt;
    }
    if (d < 16) {
      int oct = d;
      short8 hi;
      #pragma unroll
      for (int i = 0; i < 8; i++) hi[i] = bf16_rne(sctr[half][oct * 8 + i]);
      Apk[frag_idx(c, oct)] = hi;
    }
  }
}

// K2: MFMA dist. R4 body with ONE change: __launch_bounds__(256,4) so all
// 1024 blocks are co-resident in a single dispatch round (R4's (256,3) gave
// 768+256 two-round straggler tail, visible as low time-avg occupancy). The
// 128-VGPR cap this imposes doesn't fit R4's full 24-fragment prefetch
// (~140 VGPR), so the B prefetch is split into two ks-halves: peak live set
// av(32) + bhalf(32) + acc(32) ~= 100 VGPR. Two latency exposures instead of
// one, hidden by 16 waves/CU. Operand-swapped MFMA (R4-verified): lane owns
// class col=lane&31, regs span j -> lane-local epilogue.
__global__ __launch_bounds__(256, 4) void dist_kernel(
    const short8* __restrict__ Apk, const short8* __restrict__ Bpk,
    const float* __restrict__ x2, const float* __restrict__ c2,
    const int* __restrict__ targets,
    float* __restrict__ dp_part, float* __restrict__ dn_part) {
  __shared__ float sc2[64];
  __shared__ float sx2[128];
  __shared__ int stgt[128];
  __shared__ float redp[2][2][32];  // [wn][wm][class-in-tile]
  __shared__ float redn[2][2][32];

  int tid = threadIdx.x;
  int jbase = blockIdx.x * 128;
  int cbase = blockIdx.y * 64;
  int wave = tid >> 6, lane = tid & 63;
  int wm = wave >> 1, wn = wave & 1;

  if (tid < 128) {
    sx2[tid] = x2[jbase + tid];
    stgt[tid] = targets[jbase + tid];
  }
  if (tid < 64) sc2[tid] = c2[cbase + tid];

  int mtg = (cbase >> 5) + wm;       // this wave's m-tile in Apk
  int ntg0 = (jbase >> 5) + wn * 2;  // first of 2 n-tiles in Bpk

  const short8* abase  = &Apk[(size_t)(mtg * 8) * 64 + lane];
  const short8* b0base = &Bpk[(size_t)((ntg0 + 0) * 8) * 64 + lane];
  const short8* b1base = &Bpk[(size_t)((ntg0 + 1) * 8) * 64 + lane];

  // A fragments for all 8 ks (32 VGPR), B fragments staged in two halves.
  bf16x8 av[8];
  #pragma unroll
  for (int ks = 0; ks < 8; ks++) av[ks] = abase[(size_t)ks * 64];

  f32x16 acc[2];
  acc[0] = (f32x16)(0.f);
  acc[1] = (f32x16)(0.f);

  bf16x8 b0h[4], b1h[4];
  #pragma unroll
  for (int k = 0; k < 4; k++) {       // stage 1 loads: 8 in flight
    b0h[k] = b0base[(size_t)k * 64];
    b1h[k] = b1base[(size_t)k * 64];
  }
  #pragma unroll
  for (int k = 0; k < 4; k++) {       // stage 1 MFMA (swapped operands)
    acc[0] = __builtin_amdgcn_mfma_f32_32x32x16_bf16(b0h[k], av[k], acc[0], 0, 0, 0);
    acc[1] = __builtin_amdgcn_mfma_f32_32x32x16_bf16(b1h[k], av[k], acc[1], 0, 0, 0);
  }
  #pragma unroll
  for (int k = 0; k < 4; k++) {       // stage 2 loads
    b0h[k] = b0base[(size_t)(4 + k) * 64];
    b1h[k] = b1base[(size_t)(4 + k) * 64];
  }
  #pragma unroll
  for (int k = 0; k < 4; k++) {       // stage 2 MFMA
    acc[0] = __builtin_amdgcn_mfma_f32_32x32x16_bf16(b0h[k], av[4 + k], acc[0], 0, 0, 0);
    acc[1] = __builtin_amdgcn_mfma_f32_32x32x16_bf16(b1h[k], av[4 + k], acc[1], 0, 0, 0);
  }

  __syncthreads();  // staging visible

  // ---- lane-local epilogue: lane owns class col=lane&31; regs span j ----
  int col = lane & 31;
  int hf = lane >> 5;
  int c_loc = wm * 32 + col;
  int cg = cbase + c_loc;
  float c2v = sc2[c_loc];
  float pmax = -INFINITY, nmin = INFINITY;
  #pragma unroll
  for (int nt = 0; nt < 2; nt++) {
    #pragma unroll
    for (int r = 0; r < 16; r++) {
      int j_loc = wn * 64 + nt * 32 + (r & 3) + 8 * (r >> 2) + 4 * hf;
      float d2 = c2v + sx2[j_loc] - 2.f * acc[nt][r];
      if (stgt[j_loc] == cg) pmax = fmaxf(pmax, d2);
      else                   nmin = fminf(nmin, d2);
    }
  }
  // fold the two hf halves (same class, disjoint j sets)
  pmax = fmaxf(pmax, __shfl_xor(pmax, 32));
  nmin = fminf(nmin, __shfl_xor(nmin, 32));
  if (lane < 32) {
    redp[wn][wm][col] = pmax;
    redn[wn][wm][col] = nmin;
  }
  __syncthreads();
  if (tid < 64) {  // one thread per class in this block's 64-class tile
    int wmx = tid >> 5, idx = tid & 31;
    float dp = fmaxf(redp[0][wmx][idx], redp[1][wmx][idx]);
    float dn = fminf(redn[0][wmx][idx], redn[1][wmx][idx]);
    size_t slot = (size_t)blockIdx.x * NCLS + cbase + tid;
    dp_part[slot] = dp;
    dn_part[slot] = dn;
  }
}

// K3: EXACT R4-verified body. 16 blocks x 256 threads; one atomicAdd pair
// per block into out (zeroed by K1).
__global__ __launch_bounds__(256) void finalize_kernel(
    const float* __restrict__ dp_part, const float* __restrict__ dn_part,
    const int* __restrict__ counts, float* __restrict__ out) {
  __shared__ float sdp[4][64];
  __shared__ float sdn[4][64];
  int g = blockIdx.x;
  int t = threadIdx.x;
  int cl = t & 63;
  int pg = t >> 6;
  int c = g * 64 + cl;
  float dp = -INFINITY, dn = INFINITY;
  #pragma unroll
  for (int p = pg * 16; p < pg * 16 + 16; p++) {
    dp = fmaxf(dp, dp_part[(size_t)p * NCLS + c]);
    dn = fminf(dn, dn_part[(size_t)p * NCLS + c]);
  }
  sdp[pg][cl] = dp;
  sdn[pg][cl] = dn;
  __syncthreads();
  if (t < 64) {  // wave 0
    dp = fmaxf(fmaxf(sdp[0][cl], sdp[1][cl]), fmaxf(sdp[2][cl], sdp[3][cl]));
    dn = fminf(fminf(sdn[0][cl], sdn[1][cl]), fminf(sdn[2][cl], sdn[3][cl]));
    int cnt = counts[c];
    float ls = 0.f, ps = 0.f;
    if (cnt > 0) {
      ls = (float)cnt * fmaxf(dp - dn + MARGIN_V, 0.f);
      ps = (float)cnt * ((dn > dp) ? 1.f : 0.f);
    }
    #pragma unroll
    for (int sh = 32; sh > 0; sh >>= 1) {
      ls += __shfl_down(ls, sh);
      ps += __shfl_down(ps, sh);
    }
    if (t == 0) {
      atomicAdd(&out[0], ls / (float)N_SAMPLES);
      atomicAdd(&out[1], ps / (float)N_SAMPLES);
    }
  }
}

extern "C" void kernel_launch(void* const* d_in, const int* in_sizes, int n_in,
                              void* d_out, int out_size, void* d_ws, size_t ws_size,
                              hipStream_t stream) {
  const float* inputs = (const float*)d_in[0];
  const int* targets = (const int*)d_in[1];
  float* out = (float*)d_out;

  char* w = (char*)d_ws;
  float* x2 = (float*)w;            w += (size_t)N_SAMPLES * 4;
  float* c2 = (float*)w;            w += (size_t)NCLS * 4;
  int* counts = (int*)w;            w += (size_t)NCLS * 4;
  float* dp_part = (float*)w;       w += (size_t)NPART * NCLS * 4;    // 256 KB
  float* dn_part = (float*)w;       w += (size_t)NPART * NCLS * 4;    // 256 KB
  short8* Apk = (short8*)w;         w += (size_t)NCLS * DIM * 2;      // 256 KB
  short8* Bpk = (short8*)w;         w += (size_t)N_SAMPLES * DIM * 2; // 2 MB

  pack_kernel<<<N_SAMPLES / 16 + NCLS / 2, 256, 0, stream>>>(
      inputs, targets, x2, c2, counts, Apk, Bpk, out);
  dist_kernel<<<dim3(DIST_GX, DIST_GY), 256, 0, stream>>>(
      Apk, Bpk, x2, c2, targets, dp_part, dn_part);
  finalize_kernel<<<16, 256, 0, stream>>>(dp_part, dn_part, counts, out);
}

// Round 7
// 70.132 us; speedup vs baseline: 2.4204x; 1.0014x over previous
//
#include <hip/hip_runtime.h>
#include <math.h>

#define N_SAMPLES 8192
#define DIM 128
#define NCLS 1024
#define MARGIN_V 0.3f
#define DIST_GX (N_SAMPLES / 128)   // 64 j-tiles of 128
#define DIST_GY (NCLS / 64)         // 16 class-tiles of 64
#define NPART DIST_GX               // 64 partials per class
#define MAXMEM 64                   // LDS member-list capacity per class
#define PIPE 16                     // pipelined gather depth (covers P(cnt<=16)~0.997)
#define ACLS 8                      // classes per A-side pack block
#define NA (NCLS / ACLS)            // 128 A-side blocks

using bf16x8 = __attribute__((ext_vector_type(8))) short;
using f32x16 = __attribute__((ext_vector_type(16))) float;
using short8 = __attribute__((ext_vector_type(8))) short;

// LESSON (R1/R2/R3/R5): in-kernel cross-block sync (spin barrier, cooperative
// launch, last-block + __threadfence) costs 40-100+ us on MI355X (agent-scope
// release = L2 writeback on non-coherent XCDs; fused tails also wreck the
// register allocation of the hot loop). Kernel boundaries cost ~2 us. Three
// plain kernels IS the optimal sync structure here. Do not re-fuse.
// Budget model (R3/R4/R6-constrained): fill ~41 (harness, timed, fixed) +
// pack ~12 + dist ~6 + finalize ~3 + gaps ~8.

__device__ __forceinline__ short bf16_rne(float x) {
  unsigned u = __float_as_uint(x);
  unsigned r = u + 0x7FFFu + ((u >> 16) & 1u);
  return (short)(r >> 16);
}

// Packed fragment layout, single bf16 plane (row-major source [row][k]):
//   tile = row>>5, kstep = oct>>1 (oct = k/8), lane = ((oct&1)<<5)|(row&31)
//   short8 index = (tile*8 + kstep)*64 + lane
// Matches mfma_32x32x16 A/B operand layout operand[row=lane&31][k=(lane>>5)*8+j]
// (harness-verified; bf16-only passes with absmax ~0).
__device__ __forceinline__ size_t frag_idx(int row, int oct) {
  int tile = row >> 5, ks = oct >> 1, lane = ((oct & 1) << 5) | (row & 31);
  return (size_t)(tile * 8 + ks) * 64 + lane;
}

// K1: fused pack. Blocks [0,512): B-side — x2 + bf16 pack of 16 input rows
// (R4-verified body). Blocks [512,640): A-side — 8 classes/block (R7 change:
// 4x less redundant target-scan traffic, 16MB->4MB; one unsigned range-check
// instead of two equality compares; float4 gather). Block 0 zeroes out.
__global__ __launch_bounds__(256) void pack_kernel(
    const float* __restrict__ inputs, const int* __restrict__ targets,
    float* __restrict__ x2, float* __restrict__ c2, int* __restrict__ counts,
    short8* __restrict__ Apk, short8* __restrict__ Bpk, float* __restrict__ out) {
  int b = blockIdx.x;
  int tid = threadIdx.x;
  if (b == 0 && tid < 2) out[tid] = 0.f;
  if (b < N_SAMPLES / 16) {
    int row = b * 16 + (tid >> 4);
    int oct = tid & 15;
    const float4* p = (const float4*)(inputs + (size_t)row * DIM + oct * 8);
    float4 v0 = p[0], v1 = p[1];
    float v[8] = {v0.x, v0.y, v0.z, v0.w, v1.x, v1.y, v1.z, v1.w};
    float s = 0.f;
    #pragma unroll
    for (int i = 0; i < 8; i++) s += v[i] * v[i];
    #pragma unroll
    for (int m = 1; m < 16; m <<= 1) s += __shfl_xor(s, m);
    if (oct == 0) x2[row] = s;
    short8 hi;
    #pragma unroll
    for (int i = 0; i < 8; i++) hi[i] = bf16_rne(v[i]);
    Bpk[frag_idx(row, oct)] = hi;
  } else {
    __shared__ int mem[ACLS][MAXMEM];
    __shared__ int mcnt[ACLS];
    __shared__ float sctr[ACLS][DIM];   // 4 KB
    int c0 = (b - N_SAMPLES / 16) * ACLS;
    if (tid < ACLS) { mcnt[tid] = 0; mem[tid][0] = 0; }  // mem[.][0] valid even if cnt==0
    __syncthreads();
    // Vectorized batch scan: 8 x dwordx4 per thread, all in flight before
    // the LDS-atomic compare loop. Element j = 4*(tid+256*q)+e.
    const int4* tv = (const int4*)targets;
    int4 tg[8];
    #pragma unroll
    for (int q = 0; q < 8; q++) tg[q] = tv[tid + 256 * q];
    #pragma unroll
    for (int q = 0; q < 8; q++) {
      int base = 4 * (tid + 256 * q);
      int te[4] = {tg[q].x, tg[q].y, tg[q].z, tg[q].w};
      #pragma unroll
      for (int e = 0; e < 4; e++) {
        unsigned dd = (unsigned)(te[e] - c0);
        if (dd < ACLS) {   // single range-check covers all 8 classes
          int p = atomicAdd(&mcnt[dd], 1);
          if (p < MAXMEM) mem[dd][p] = base + e;
        }
      }
    }
    __syncthreads();
    // 32 threads per class; thread t owns dims [4t, 4t+4) as a float4.
    int k = tid >> 5;       // class-in-block
    int t = tid & 31;       // thread-in-class
    int c = c0 + k;
    int cnt = mcnt[k];
    int cl = (cnt < MAXMEM) ? cnt : MAXMEM;
    int n1 = (cl < PIPE) ? cl : PIPE;
    int idxs[PIPE];
    #pragma unroll
    for (int i = 0; i < PIPE; i++) idxs[i] = mem[k][(i < n1) ? i : 0];
    float4 vbuf[PIPE];
    #pragma unroll
    for (int i = 0; i < PIPE; i++)
      vbuf[i] = *(const float4*)(inputs + (size_t)idxs[i] * DIM + t * 4);
    float a0 = 0.f, a1 = 0.f, a2 = 0.f, a3 = 0.f;
    #pragma unroll
    for (int i = 0; i < PIPE; i++) {
      if (i < n1) { a0 += vbuf[i].x; a1 += vbuf[i].y; a2 += vbuf[i].z; a3 += vbuf[i].w; }
    }
    for (int m = PIPE; m < cl; m++) {
      float4 vm = *(const float4*)(inputs + (size_t)mem[k][m] * DIM + t * 4);
      a0 += vm.x; a1 += vm.y; a2 += vm.z; a3 += vm.w;
    }
    float inv = (cnt > 0) ? 1.f / (float)cnt : 0.f;
    a0 *= inv; a1 *= inv; a2 *= inv; a3 *= inv;
    sctr[k][t * 4 + 0] = a0;
    sctr[k][t * 4 + 1] = a1;
    sctr[k][t * 4 + 2] = a2;
    sctr[k][t * 4 + 3] = a3;
    float vv = a0 * a0 + a1 * a1 + a2 * a2 + a3 * a3;
    #pragma unroll
    for (int sh = 16; sh > 0; sh >>= 1) vv += __shfl_down(vv, sh);
    if (t == 0) {           // lane base of each 32-group: full 128-dim sum
      c2[c] = vv;
      counts[c] = cnt;
    }
    __syncthreads();
    if (tid < ACLS * 16) {  // 128 threads pack Apk: class=tid>>4, oct=tid&15
      int kk = tid >> 4, oct = tid & 15;
      short8 hi;
      #pragma unroll
      for (int i = 0; i < 8; i++) hi[i] = bf16_rne(sctr[kk][oct * 8 + i]);
      Apk[frag_idx(c0 + kk, oct)] = hi;
    }
  }
}

// K2: MFMA dist — EXACT R6 body (neutral vs R4, structurally cleaner:
// (256,4) -> all 1024 blocks co-resident in one dispatch round; B prefetch
// split in two ks-halves to fit the 128-VGPR cap; operand-swapped MFMA so
// lane owns class col=lane&31 and the epilogue is lane-local VALU).
__global__ __launch_bounds__(256, 4) void dist_kernel(
    const short8* __restrict__ Apk, const short8* __restrict__ Bpk,
    const float* __restrict__ x2, const float* __restrict__ c2,
    const int* __restrict__ targets,
    float* __restrict__ dp_part, float* __restrict__ dn_part) {
  __shared__ float sc2[64];
  __shared__ float sx2[128];
  __shared__ int stgt[128];
  __shared__ float redp[2][2][32];  // [wn][wm][class-in-tile]
  __shared__ float redn[2][2][32];

  int tid = threadIdx.x;
  int jbase = blockIdx.x * 128;
  int cbase = blockIdx.y * 64;
  int wave = tid >> 6, lane = tid & 63;
  int wm = wave >> 1, wn = wave & 1;

  if (tid < 128) {
    sx2[tid] = x2[jbase + tid];
    stgt[tid] = targets[jbase + tid];
  }
  if (tid < 64) sc2[tid] = c2[cbase + tid];

  int mtg = (cbase >> 5) + wm;       // this wave's m-tile in Apk
  int ntg0 = (jbase >> 5) + wn * 2;  // first of 2 n-tiles in Bpk

  const short8* abase  = &Apk[(size_t)(mtg * 8) * 64 + lane];
  const short8* b0base = &Bpk[(size_t)((ntg0 + 0) * 8) * 64 + lane];
  const short8* b1base = &Bpk[(size_t)((ntg0 + 1) * 8) * 64 + lane];

  // A fragments for all 8 ks (32 VGPR), B fragments staged in two halves.
  bf16x8 av[8];
  #pragma unroll
  for (int ks = 0; ks < 8; ks++) av[ks] = abase[(size_t)ks * 64];

  f32x16 acc[2];
  acc[0] = (f32x16)(0.f);
  acc[1] = (f32x16)(0.f);

  bf16x8 b0h[4], b1h[4];
  #pragma unroll
  for (int k = 0; k < 4; k++) {       // stage 1 loads: 8 in flight
    b0h[k] = b0base[(size_t)k * 64];
    b1h[k] = b1base[(size_t)k * 64];
  }
  #pragma unroll
  for (int k = 0; k < 4; k++) {       // stage 1 MFMA (swapped operands)
    acc[0] = __builtin_amdgcn_mfma_f32_32x32x16_bf16(b0h[k], av[k], acc[0], 0, 0, 0);
    acc[1] = __builtin_amdgcn_mfma_f32_32x32x16_bf16(b1h[k], av[k], acc[1], 0, 0, 0);
  }
  #pragma unroll
  for (int k = 0; k < 4; k++) {       // stage 2 loads
    b0h[k] = b0base[(size_t)(4 + k) * 64];
    b1h[k] = b1base[(size_t)(4 + k) * 64];
  }
  #pragma unroll
  for (int k = 0; k < 4; k++) {       // stage 2 MFMA
    acc[0] = __builtin_amdgcn_mfma_f32_32x32x16_bf16(b0h[k], av[4 + k], acc[0], 0, 0, 0);
    acc[1] = __builtin_amdgcn_mfma_f32_32x32x16_bf16(b1h[k], av[4 + k], acc[1], 0, 0, 0);
  }

  __syncthreads();  // staging visible

  // ---- lane-local epilogue: lane owns class col=lane&31; regs span j ----
  int col = lane & 31;
  int hf = lane >> 5;
  int c_loc = wm * 32 + col;
  int cg = cbase + c_loc;
  float c2v = sc2[c_loc];
  float pmax = -INFINITY, nmin = INFINITY;
  #pragma unroll
  for (int nt = 0; nt < 2; nt++) {
    #pragma unroll
    for (int r = 0; r < 16; r++) {
      int j_loc = wn * 64 + nt * 32 + (r & 3) + 8 * (r >> 2) + 4 * hf;
      float d2 = c2v + sx2[j_loc] - 2.f * acc[nt][r];
      if (stgt[j_loc] == cg) pmax = fmaxf(pmax, d2);
      else                   nmin = fminf(nmin, d2);
    }
  }
  // fold the two hf halves (same class, disjoint j sets)
  pmax = fmaxf(pmax, __shfl_xor(pmax, 32));
  nmin = fminf(nmin, __shfl_xor(nmin, 32));
  if (lane < 32) {
    redp[wn][wm][col] = pmax;
    redn[wn][wm][col] = nmin;
  }
  __syncthreads();
  if (tid < 64) {  // one thread per class in this block's 64-class tile
    int wmx = tid >> 5, idx = tid & 31;
    float dp = fmaxf(redp[0][wmx][idx], redp[1][wmx][idx]);
    float dn = fminf(redn[0][wmx][idx], redn[1][wmx][idx]);
    size_t slot = (size_t)blockIdx.x * NCLS + cbase + tid;
    dp_part[slot] = dp;
    dn_part[slot] = dn;
  }
}

// K3: EXACT R4-verified body. 16 blocks x 256 threads; one atomicAdd pair
// per block into out (zeroed by K1).
__global__ __launch_bounds__(256) void finalize_kernel(
    const float* __restrict__ dp_part, const float* __restrict__ dn_part,
    const int* __restrict__ counts, float* __restrict__ out) {
  __shared__ float sdp[4][64];
  __shared__ float sdn[4][64];
  int g = blockIdx.x;
  int t = threadIdx.x;
  int cl = t & 63;
  int pg = t >> 6;
  int c = g * 64 + cl;
  float dp = -INFINITY, dn = INFINITY;
  #pragma unroll
  for (int p = pg * 16; p < pg * 16 + 16; p++) {
    dp = fmaxf(dp, dp_part[(size_t)p * NCLS + c]);
    dn = fminf(dn, dn_part[(size_t)p * NCLS + c]);
  }
  sdp[pg][cl] = dp;
  sdn[pg][cl] = dn;
  __syncthreads();
  if (t < 64) {  // wave 0
    dp = fmaxf(fmaxf(sdp[0][cl], sdp[1][cl]), fmaxf(sdp[2][cl], sdp[3][cl]));
    dn = fminf(fminf(sdn[0][cl], sdn[1][cl]), fminf(sdn[2][cl], sdn[3][cl]));
    int cnt = counts[c];
    float ls = 0.f, ps = 0.f;
    if (cnt > 0) {
      ls = (float)cnt * fmaxf(dp - dn + MARGIN_V, 0.f);
      ps = (float)cnt * ((dn > dp) ? 1.f : 0.f);
    }
    #pragma unroll
    for (int sh = 32; sh > 0; sh >>= 1) {
      ls += __shfl_down(ls, sh);
      ps += __shfl_down(ps, sh);
    }
    if (t == 0) {
      atomicAdd(&out[0], ls / (float)N_SAMPLES);
      atomicAdd(&out[1], ps / (float)N_SAMPLES);
    }
  }
}

extern "C" void kernel_launch(void* const* d_in, const int* in_sizes, int n_in,
                              void* d_out, int out_size, void* d_ws, size_t ws_size,
                              hipStream_t stream) {
  const float* inputs = (const float*)d_in[0];
  const int* targets = (const int*)d_in[1];
  float* out = (float*)d_out;

  char* w = (char*)d_ws;
  float* x2 = (float*)w;            w += (size_t)N_SAMPLES * 4;
  float* c2 = (float*)w;            w += (size_t)NCLS * 4;
  int* counts = (int*)w;            w += (size_t)NCLS * 4;
  float* dp_part = (float*)w;       w += (size_t)NPART * NCLS * 4;    // 256 KB
  float* dn_part = (float*)w;       w += (size_t)NPART * NCLS * 4;    // 256 KB
  short8* Apk = (short8*)w;         w += (size_t)NCLS * DIM * 2;      // 256 KB
  short8* Bpk = (short8*)w;         w += (size_t)N_SAMPLES * DIM * 2; // 2 MB

  pack_kernel<<<N_SAMPLES / 16 + NA, 256, 0, stream>>>(
      inputs, targets, x2, c2, counts, Apk, Bpk, out);
  dist_kernel<<<dim3(DIST_GX, DIST_GY), 256, 0, stream>>>(
      Apk, Bpk, x2, c2, targets, dp_part, dn_part);
  finalize_kernel<<<16, 256, 0, stream>>>(dp_part, dn_part, counts, out);
}